// Round 1
// baseline (477.748 us; speedup 1.0000x reference)
//
#include <hip/hip_runtime.h>

// Problem shape (fixed by setup_inputs): inputs [B=32, T=4096, F=256] fp32.
constexpr int B_ = 32;
constexpr int T_ = 4096;
constexpr int F_ = 256;
constexpr int CHUNKS = 256;         // chunks along T (4x more waves than before)
constexpr int L_ = T_ / CHUNKS;     // 16 steps per chunk
constexpr int WPB = 4;              // waves (=chunks) per block
constexpr float EPS_ = 1e-6f;

// ---- ordered-uint encoding for float atomic min/max (handles any sign) ----
__device__ __forceinline__ unsigned f2ord(float f) {
    unsigned u = __float_as_uint(f);
    return (u & 0x80000000u) ? ~u : (u | 0x80000000u);
}
__device__ __forceinline__ float ord2f(unsigned u) {
    return (u & 0x80000000u) ? __uint_as_float(u ^ 0x80000000u)
                             : __uint_as_float(~u);
}

__device__ __forceinline__ float clamp01(float v) {
    return fminf(fmaxf(v, 0.0f), 1.0f);
}

// ---------------------------------------------------------------------------
// Kernel A: chunk-local EMA with zero seed; emit end-state E[b][c][f].
// One wave per (b,c); lane handles 4 consecutive f via float4.
// 4 chunks per 256-thread block; cap VGPR for 8 waves/SIMD (32 waves/CU).
// ---------------------------------------------------------------------------
__global__ __launch_bounds__(256, 8) void ema_chunk_local(
        const float* __restrict__ x, const float* __restrict__ smooth,
        float* __restrict__ E) {
    const int wid  = threadIdx.x >> 6;
    const int lane = threadIdx.x & 63;
    const int bc   = blockIdx.x * WPB + wid;   // b*CHUNKS + c (contiguous)
    const float w = clamp01(smooth[0]);
    const float d = 1.0f - w;

    const float4* xp = reinterpret_cast<const float4*>(
                           x + (size_t)bc * L_ * F_) + lane;
    float4 a = make_float4(0.f, 0.f, 0.f, 0.f);

    for (int t0 = 0; t0 < L_; t0 += 8) {
        float4 v[8];
#pragma unroll
        for (int i = 0; i < 8; ++i) v[i] = xp[(size_t)(t0 + i) * (F_ / 4)];
#pragma unroll
        for (int i = 0; i < 8; ++i) {
            a.x = fmaf(w, v[i].x, d * a.x);
            a.y = fmaf(w, v[i].y, d * a.y);
            a.z = fmaf(w, v[i].z, d * a.z);
            a.w = fmaf(w, v[i].w, d * a.w);
        }
    }
    reinterpret_cast<float4*>(E + (size_t)bc * F_)[lane] = a;
}

// ---------------------------------------------------------------------------
// Kernel B: cross-chunk carry scan. In_0 = x[b,0,f] (reference initial state);
// In_c = d^L * In_{c-1} + E_{c-1}. Also initializes the min/max atomic slots.
// One wave per b; lane handles 4 f via float4. Contraction (d^L < 1) keeps
// the regrouping error bounded (~ulp), independent of CHUNKS.
// ---------------------------------------------------------------------------
__global__ __launch_bounds__(64) void ema_carry(
        const float* __restrict__ x, const float* __restrict__ smooth,
        const float* __restrict__ E, float* __restrict__ In,
        unsigned* __restrict__ mm) {
    const int b = blockIdx.x;
    const int lane = threadIdx.x;
    if (b == 0 && lane == 0) {
        mm[0] = 0xFFFFFFFFu;  // ordered-min init (= +inf)
        mm[1] = 0x00000000u;  // ordered-max init (= -inf)
    }
    const float w = clamp01(smooth[0]);
    const float d = 1.0f - w;
    // dL = d^16 via repeated squaring (4 muls) — avoids libm powf
    float dL = d;
    dL *= dL;  // d^2
    dL *= dL;  // d^4
    dL *= dL;  // d^8
    dL *= dL;  // d^16
    static_assert(L_ == 16, "dL squaring chain assumes L_ == 16");

    float4 cur = reinterpret_cast<const float4*>(
                     x + (size_t)b * T_ * F_)[lane];
    for (int c = 0; c < CHUNKS; ++c) {
        const size_t idx = ((size_t)b * CHUNKS + c) * (F_ / 4) + lane;
        reinterpret_cast<float4*>(In)[idx] = cur;
        const float4 e = reinterpret_cast<const float4*>(E)[idx];
        cur.x = fmaf(dL, cur.x, e.x);
        cur.y = fmaf(dL, cur.y, e.y);
        cur.z = fmaf(dL, cur.z, e.z);
        cur.w = fmaf(dL, cur.w, e.w);
    }
}

// ---------------------------------------------------------------------------
// Kernel C: seeded re-scan + PCEN compression + global min/max reduction.
// out_pre = (x*(EPS+ema)^-g + bias)^(1/r) - bias^(1/r)
// ---------------------------------------------------------------------------
__device__ __forceinline__ float pcen_elem(float xv, float av, float g,
                                           float inv_r, float bias,
                                           float bpow) {
    // (eps+a)^-g  via exp2/log2 (v_exp_f32 / v_log_f32)
    const float p = __builtin_exp2f(-g * __builtin_log2f(EPS_ + av));
    const float base = fmaf(xv, p, bias);              // >= bias > 0
    return __builtin_exp2f(inv_r * __builtin_log2f(base)) - bpow;
}

__global__ __launch_bounds__(256, 8) void pcen_out(
        const float* __restrict__ x, const float* __restrict__ In,
        const float* __restrict__ gain, const float* __restrict__ bias_p,
        const float* __restrict__ root, const float* __restrict__ smooth,
        float* __restrict__ out, unsigned* __restrict__ mm) {
    const int wid  = threadIdx.x >> 6;
    const int lane = threadIdx.x & 63;
    const int bc   = blockIdx.x * WPB + wid;
    const float w = clamp01(smooth[0]);
    const float d = 1.0f - w;
    const float g = fminf(gain[0], 1.0f);
    const float r = fmaxf(root[0], 1.0f);
    const float inv_r = 1.0f / r;
    const float bias = bias_p[0];
    const float bpow = __builtin_exp2f(inv_r * __builtin_log2f(bias));

    const float4* xp = reinterpret_cast<const float4*>(
                           x + (size_t)bc * L_ * F_) + lane;
    float4* op = reinterpret_cast<float4*>(
                     out + (size_t)bc * L_ * F_) + lane;
    float4 a = reinterpret_cast<const float4*>(In)[(size_t)bc * (F_ / 4) + lane];

    float lmin = __builtin_inff(), lmax = -__builtin_inff();
    for (int t0 = 0; t0 < L_; t0 += 8) {
        float4 v[8];
#pragma unroll
        for (int i = 0; i < 8; ++i) v[i] = xp[(size_t)(t0 + i) * (F_ / 4)];
#pragma unroll
        for (int i = 0; i < 8; ++i) {
            a.x = fmaf(w, v[i].x, d * a.x);
            a.y = fmaf(w, v[i].y, d * a.y);
            a.z = fmaf(w, v[i].z, d * a.z);
            a.w = fmaf(w, v[i].w, d * a.w);
            float4 o;
            o.x = pcen_elem(v[i].x, a.x, g, inv_r, bias, bpow);
            o.y = pcen_elem(v[i].y, a.y, g, inv_r, bias, bpow);
            o.z = pcen_elem(v[i].z, a.z, g, inv_r, bias, bpow);
            o.w = pcen_elem(v[i].w, a.w, g, inv_r, bias, bpow);
            lmin = fminf(lmin, fminf(fminf(o.x, o.y), fminf(o.z, o.w)));
            lmax = fmaxf(lmax, fmaxf(fmaxf(o.x, o.y), fmaxf(o.z, o.w)));
            op[(size_t)(t0 + i) * (F_ / 4)] = o;
        }
    }
    // wave-level (64-lane) butterfly reduction, then one atomic pair per wave
#pragma unroll
    for (int off = 32; off > 0; off >>= 1) {
        lmin = fminf(lmin, __shfl_xor(lmin, off));
        lmax = fmaxf(lmax, __shfl_xor(lmax, off));
    }
    if (lane == 0) {
        atomicMin(&mm[0], f2ord(lmin));
        atomicMax(&mm[1], f2ord(lmax));
    }
}

// ---------------------------------------------------------------------------
// Kernel D: in-place global min/max normalization: out = out*s + o
// ---------------------------------------------------------------------------
__global__ __launch_bounds__(256) void norm_apply(
        float* __restrict__ out, const unsigned* __restrict__ mm, int n4) {
    const float mn = ord2f(mm[0]);
    const float mx = ord2f(mm[1]);
    const float s = 2.0f / (mx - mn);
    const float o = fmaf(-mn, s, -1.0f);
    float4* p = reinterpret_cast<float4*>(out);
    const int stride = gridDim.x * blockDim.x;
    for (int i = blockIdx.x * blockDim.x + threadIdx.x; i < n4; i += stride) {
        float4 v = p[i];
        v.x = fmaf(v.x, s, o);
        v.y = fmaf(v.y, s, o);
        v.z = fmaf(v.z, s, o);
        v.w = fmaf(v.w, s, o);
        p[i] = v;
    }
}

extern "C" void kernel_launch(void* const* d_in, const int* in_sizes, int n_in,
                              void* d_out, int out_size, void* d_ws, size_t ws_size,
                              hipStream_t stream) {
    const float* x      = (const float*)d_in[0];
    const float* gain   = (const float*)d_in[1];
    const float* bias   = (const float*)d_in[2];
    const float* root   = (const float*)d_in[3];
    const float* smooth = (const float*)d_in[4];
    float* out = (float*)d_out;

    // ws layout: E [B*CHUNKS*F] | In [B*CHUNKS*F] | mm[2]  (~16 MiB + 8 B)
    float* E  = (float*)d_ws;
    float* In = E + (size_t)B_ * CHUNKS * F_;
    unsigned* mm = (unsigned*)(In + (size_t)B_ * CHUNKS * F_);

    ema_chunk_local<<<(B_ * CHUNKS) / WPB, 256, 0, stream>>>(x, smooth, E);
    ema_carry<<<B_, 64, 0, stream>>>(x, smooth, E, In, mm);
    pcen_out<<<(B_ * CHUNKS) / WPB, 256, 0, stream>>>(x, In, gain, bias, root,
                                                      smooth, out, mm);
    norm_apply<<<2048, 256, 0, stream>>>(out, mm, (B_ * T_ * F_) / 4);
}

// Round 2
// 313.594 us; speedup vs baseline: 1.5235x; 1.5235x over previous
//
#include <hip/hip_runtime.h>

// Problem shape (fixed by setup_inputs): inputs [B=32, T=4096, F=256] fp32.
constexpr int B_ = 32;
constexpr int T_ = 4096;
constexpr int F_ = 256;
constexpr int F4 = F_ / 4;
constexpr int CHUNKS = 64;          // chunks along T
constexpr int L_ = T_ / CHUNKS;     // 64 timesteps per chunk
constexpr int ST = 8;               // timesteps per LDS slice (8 KB)
constexpr int NS = L_ / ST;         // 8 slices per chunk
constexpr int WPB = 4;              // waves (=chunks) per 256-thread block
constexpr float EPS_ = 1e-6f;

// ---- ordered-uint encoding for float atomic min/max (handles any sign) ----
__device__ __forceinline__ unsigned f2ord(float f) {
    unsigned u = __float_as_uint(f);
    return (u & 0x80000000u) ? ~u : (u | 0x80000000u);
}
__device__ __forceinline__ float ord2f(unsigned u) {
    return (u & 0x80000000u) ? __uint_as_float(u ^ 0x80000000u)
                             : __uint_as_float(~u);
}
__device__ __forceinline__ float clamp01(float v) {
    return fminf(fmaxf(v, 0.0f), 1.0f);
}

// ---- async global->LDS staging (16 B per lane; LDS dest is wave-uniform) ----
typedef const __attribute__((address_space(1))) unsigned GU;
typedef __attribute__((address_space(3))) unsigned LU;

__device__ __forceinline__ void async_row16(const float* g, float* l) {
    __builtin_amdgcn_global_load_lds((GU*)g, (LU*)l, 16, 0, 0);
}
// Issue one slice: ST rows of 1 KB. gbase = chunk row 0 of slice; lbase uniform.
__device__ __forceinline__ void issue_slice(const float* gbase, float* lbase,
                                            int lane) {
#pragma unroll
    for (int t = 0; t < ST; ++t)
        async_row16(gbase + (size_t)t * F_ + lane * 4, lbase + t * F_);
}
// Counted waits. vmcnt(8): everything except the 8 newest (= just-issued next
// slice) has retired -> current slice's DMA writes have landed in LDS.
__device__ __forceinline__ void wait_vm8() {
    asm volatile("s_waitcnt vmcnt(8)" ::: "memory");
    __builtin_amdgcn_sched_barrier(0);
}
__device__ __forceinline__ void wait_vm0() {
    asm volatile("s_waitcnt vmcnt(0)" ::: "memory");
    __builtin_amdgcn_sched_barrier(0);
}

#define EMA4(a, v)                    \
    a.x = fmaf(w, (v).x, d * a.x);    \
    a.y = fmaf(w, (v).y, d * a.y);    \
    a.z = fmaf(w, (v).z, d * a.z);    \
    a.w = fmaf(w, (v).w, d * a.w)

__device__ __forceinline__ float pcen_elem(float xv, float av, float g,
                                           float inv_r, float bias,
                                           float bpow) {
    const float p = __builtin_exp2f(-g * __builtin_log2f(EPS_ + av));
    const float base = fmaf(xv, p, bias);              // >= bias > 0
    return __builtin_exp2f(inv_r * __builtin_log2f(base)) - bpow;
}

// ---------------------------------------------------------------------------
// Kernel A: chunk-local EMA with zero seed; emit end-state E[b][c][f].
// One wave per chunk; the chunk streams through a private LDS double buffer.
// LDS 64 KB/block -> 2 blocks/CU; MLP comes from the DMA queue, not VGPRs.
// ---------------------------------------------------------------------------
__global__ __launch_bounds__(256) void ema_chunk_local(
        const float* __restrict__ x, const float* __restrict__ smooth,
        float* __restrict__ E) {
    __shared__ float stage[WPB][2][ST * F_];
    const int wid  = threadIdx.x >> 6;
    const int lane = threadIdx.x & 63;
    const int bc   = blockIdx.x * WPB + wid;
    const float w = clamp01(smooth[0]);
    const float d = 1.0f - w;
    const float* xc = x + (size_t)bc * L_ * F_;

    issue_slice(xc, stage[wid][0], lane);
    float4 a = make_float4(0.f, 0.f, 0.f, 0.f);
    for (int s = 0; s < NS; ++s) {
        const int cb = s & 1;
        if (s + 1 < NS) {
            issue_slice(xc + (size_t)(s + 1) * ST * F_, stage[wid][cb ^ 1], lane);
            wait_vm8();
        } else {
            wait_vm0();
        }
        const float4* rows = reinterpret_cast<const float4*>(stage[wid][cb]);
#pragma unroll
        for (int t = 0; t < ST; ++t) {
            float4 v = rows[t * F4 + lane];
            EMA4(a, v);
        }
    }
    reinterpret_cast<float4*>(E + (size_t)bc * F_)[lane] = a;
}

// ---------------------------------------------------------------------------
// Kernel B: cross-chunk carry scan. In_0 = x[b,0,f]; In_c = d^L*In_{c-1} + E_{c-1}.
// One wave per b; 8-deep batched E prefetch. Also inits the min/max slots.
// ---------------------------------------------------------------------------
__global__ __launch_bounds__(64) void ema_carry(
        const float* __restrict__ x, const float* __restrict__ smooth,
        const float* __restrict__ E, float* __restrict__ In,
        unsigned* __restrict__ mm) {
    const int b = blockIdx.x;
    const int lane = threadIdx.x;
    if (b == 0 && lane == 0) {
        mm[0] = 0xFFFFFFFFu;  // ordered-min init (= +inf)
        mm[1] = 0x00000000u;  // ordered-max init (= -inf)
    }
    const float w = clamp01(smooth[0]);
    const float d = 1.0f - w;
    float dL = d;             // d^64 via 6 squarings
    dL *= dL; dL *= dL; dL *= dL; dL *= dL; dL *= dL; dL *= dL;
    static_assert(L_ == 64, "dL squaring chain assumes L_ == 64");

    float4 cur = reinterpret_cast<const float4*>(x + (size_t)b * T_ * F_)[lane];
    for (int c0 = 0; c0 < CHUNKS; c0 += 8) {
        float4 e[8];
#pragma unroll
        for (int i = 0; i < 8; ++i)
            e[i] = reinterpret_cast<const float4*>(E)[
                       ((size_t)b * CHUNKS + c0 + i) * F4 + lane];
#pragma unroll
        for (int i = 0; i < 8; ++i) {
            reinterpret_cast<float4*>(In)[((size_t)b * CHUNKS + c0 + i) * F4 + lane] = cur;
            cur.x = fmaf(dL, cur.x, e[i].x);
            cur.y = fmaf(dL, cur.y, e[i].y);
            cur.z = fmaf(dL, cur.z, e[i].z);
            cur.w = fmaf(dL, cur.w, e[i].w);
        }
    }
}

// ---------------------------------------------------------------------------
// Kernel C: seeded re-scan + PCEN + global min/max reduction. NO output write
// (out is recomputed in kernel D) -- saves 128 MB of HBM traffic.
// ---------------------------------------------------------------------------
__global__ __launch_bounds__(256) void pcen_minmax(
        const float* __restrict__ x, const float* __restrict__ In,
        const float* __restrict__ gain, const float* __restrict__ bias_p,
        const float* __restrict__ root, const float* __restrict__ smooth,
        unsigned* __restrict__ mm) {
    __shared__ float stage[WPB][2][ST * F_];
    __shared__ float red[2][WPB];
    const int wid  = threadIdx.x >> 6;
    const int lane = threadIdx.x & 63;
    const int bc   = blockIdx.x * WPB + wid;
    const float w = clamp01(smooth[0]);
    const float d = 1.0f - w;
    const float g = fminf(gain[0], 1.0f);
    const float r = fmaxf(root[0], 1.0f);
    const float inv_r = 1.0f / r;
    const float bias = bias_p[0];
    const float bpow = __builtin_exp2f(inv_r * __builtin_log2f(bias));
    const float* xc = x + (size_t)bc * L_ * F_;

    float4 a = reinterpret_cast<const float4*>(In)[(size_t)bc * F4 + lane];
    issue_slice(xc, stage[wid][0], lane);
    float lmin = __builtin_inff(), lmax = -__builtin_inff();
    for (int s = 0; s < NS; ++s) {
        const int cb = s & 1;
        if (s + 1 < NS) {
            issue_slice(xc + (size_t)(s + 1) * ST * F_, stage[wid][cb ^ 1], lane);
            wait_vm8();
        } else {
            wait_vm0();
        }
        const float4* rows = reinterpret_cast<const float4*>(stage[wid][cb]);
#pragma unroll
        for (int t = 0; t < ST; ++t) {
            float4 v = rows[t * F4 + lane];
            EMA4(a, v);
            float4 o;
            o.x = pcen_elem(v.x, a.x, g, inv_r, bias, bpow);
            o.y = pcen_elem(v.y, a.y, g, inv_r, bias, bpow);
            o.z = pcen_elem(v.z, a.z, g, inv_r, bias, bpow);
            o.w = pcen_elem(v.w, a.w, g, inv_r, bias, bpow);
            lmin = fminf(lmin, fminf(fminf(o.x, o.y), fminf(o.z, o.w)));
            lmax = fmaxf(lmax, fmaxf(fmaxf(o.x, o.y), fmaxf(o.z, o.w)));
        }
    }
#pragma unroll
    for (int off = 32; off > 0; off >>= 1) {
        lmin = fminf(lmin, __shfl_xor(lmin, off));
        lmax = fmaxf(lmax, __shfl_xor(lmax, off));
    }
    if (lane == 0) { red[0][wid] = lmin; red[1][wid] = lmax; }
    __syncthreads();
    if (threadIdx.x == 0) {
        float bmin = red[0][0], bmax = red[1][0];
#pragma unroll
        for (int i = 1; i < WPB; ++i) {
            bmin = fminf(bmin, red[0][i]);
            bmax = fmaxf(bmax, red[1][i]);
        }
        atomicMin(&mm[0], f2ord(bmin));
        atomicMax(&mm[1], f2ord(bmax));
    }
}

// ---------------------------------------------------------------------------
// Kernel D: re-read x (L3-warm), recompute seeded EMA + PCEN bitwise-
// identically, apply global min/max normalization, write out once.
// ---------------------------------------------------------------------------
__global__ __launch_bounds__(256) void pcen_norm_out(
        const float* __restrict__ x, const float* __restrict__ In,
        const float* __restrict__ gain, const float* __restrict__ bias_p,
        const float* __restrict__ root, const float* __restrict__ smooth,
        const unsigned* __restrict__ mm, float* __restrict__ out) {
    __shared__ float stage[WPB][2][ST * F_];
    const int wid  = threadIdx.x >> 6;
    const int lane = threadIdx.x & 63;
    const int bc   = blockIdx.x * WPB + wid;
    const float w = clamp01(smooth[0]);
    const float d = 1.0f - w;
    const float g = fminf(gain[0], 1.0f);
    const float r = fmaxf(root[0], 1.0f);
    const float inv_r = 1.0f / r;
    const float bias = bias_p[0];
    const float bpow = __builtin_exp2f(inv_r * __builtin_log2f(bias));
    const float mn = ord2f(mm[0]);
    const float mx = ord2f(mm[1]);
    const float sc = 2.0f / (mx - mn);
    const float of = fmaf(-mn, sc, -1.0f);
    const float* xc = x + (size_t)bc * L_ * F_;
    float4* oc = reinterpret_cast<float4*>(out + (size_t)bc * L_ * F_);

    float4 a = reinterpret_cast<const float4*>(In)[(size_t)bc * F4 + lane];
    issue_slice(xc, stage[wid][0], lane);
    for (int s = 0; s < NS; ++s) {
        const int cb = s & 1;
        if (s + 1 < NS) {
            issue_slice(xc + (size_t)(s + 1) * ST * F_, stage[wid][cb ^ 1], lane);
            wait_vm8();
        } else {
            wait_vm0();
        }
        const float4* rows = reinterpret_cast<const float4*>(stage[wid][cb]);
#pragma unroll
        for (int t = 0; t < ST; ++t) {
            float4 v = rows[t * F4 + lane];
            EMA4(a, v);
            float4 o;
            o.x = fmaf(pcen_elem(v.x, a.x, g, inv_r, bias, bpow), sc, of);
            o.y = fmaf(pcen_elem(v.y, a.y, g, inv_r, bias, bpow), sc, of);
            o.z = fmaf(pcen_elem(v.z, a.z, g, inv_r, bias, bpow), sc, of);
            o.w = fmaf(pcen_elem(v.w, a.w, g, inv_r, bias, bpow), sc, of);
            oc[(size_t)(s * ST + t) * F4 + lane] = o;
        }
    }
}

extern "C" void kernel_launch(void* const* d_in, const int* in_sizes, int n_in,
                              void* d_out, int out_size, void* d_ws, size_t ws_size,
                              hipStream_t stream) {
    const float* x      = (const float*)d_in[0];
    const float* gain   = (const float*)d_in[1];
    const float* bias   = (const float*)d_in[2];
    const float* root   = (const float*)d_in[3];
    const float* smooth = (const float*)d_in[4];
    float* out = (float*)d_out;

    // ws layout: E [B*CHUNKS*F] | In [B*CHUNKS*F] | mm[2]  (~4 MiB + 8 B)
    float* E  = (float*)d_ws;
    float* In = E + (size_t)B_ * CHUNKS * F_;
    unsigned* mm = (unsigned*)(In + (size_t)B_ * CHUNKS * F_);

    const int nblk = (B_ * CHUNKS) / WPB;   // 512
    ema_chunk_local<<<nblk, 256, 0, stream>>>(x, smooth, E);
    ema_carry<<<B_, 64, 0, stream>>>(x, smooth, E, In, mm);
    pcen_minmax<<<nblk, 256, 0, stream>>>(x, In, gain, bias, root, smooth, mm);
    pcen_norm_out<<<nblk, 256, 0, stream>>>(x, In, gain, bias, root, smooth,
                                            mm, out);
}